// Round 4
// baseline (807.483 us; speedup 1.0000x reference)
//
#include <hip/hip_runtime.h>

typedef short v8s __attribute__((ext_vector_type(8)));   // 8 bf16 (4 VGPRs) MFMA frag
typedef float v4f __attribute__((ext_vector_type(4)));   // 4 f32 MFMA acc

#define GAMMA_F       ((float)(5.0/3.0))
#define GM1_F         ((float)(5.0/3.0 - 1.0))
#define G_OVER_GM1_F  2.5f

// ws layout (shorts): ws1 = W1 frags [e][mt][hl][lane][8]  = 8*4*2*64*8  shorts (64KB)
//                     ws2 = W2 frags [e][ks][mt][hl][lane][8] = 8*2*4*2*64*8 shorts (128KB)
#define WS1_SHORTS (8 * 4 * 2 * 64 * 8)

__device__ __forceinline__ float rcp_f(float x){ return __builtin_amdgcn_rcpf(x); }
__device__ __forceinline__ float rsq_f(float x){ return __builtin_amdgcn_rsqf(x); }
__device__ __forceinline__ float fdiv(float a, float b){ return a * __builtin_amdgcn_rcpf(b); }

__device__ __forceinline__ float fast_tanh(float x){
    float e = __expf(2.0f * x);
    return fmaf(-2.0f, rcp_f(e + 1.0f), 1.0f);
}

// exact RTNE float->bf16 bit math
__device__ __forceinline__ unsigned bfbits(float f){
    unsigned u = __builtin_bit_cast(unsigned, f);
    return (u + 0x7FFFu + ((u >> 16) & 1u)) >> 16;
}
__device__ __forceinline__ void split2(float f, unsigned& hi, unsigned& lo){
    hi = bfbits(f);
    float fh = __builtin_bit_cast(float, hi << 16);
    lo = bfbits(f - fh);
}

// RTNE packed pair via v_cvt_pk_bf16_f32 (no builtin on gfx950 -> inline asm;
// RTNE semantics == bfbits bit math). Result: lo16 = bf16(a), hi16 = bf16(b).
__device__ __forceinline__ unsigned pk_bf16_rn(float a, float b){
    unsigned r;
    asm("v_cvt_pk_bf16_f32 %0, %1, %2" : "=v"(r) : "v"(a), "v"(b));
    return r;
}
// 4 floats -> hi-pack uint2 + lo-pack uint2 (hi + lo == split-bf16, RTNE both)
__device__ __forceinline__ void split_pack4(const float t0, const float t1, const float t2, const float t3,
                                            uint2& hi, uint2& lo){
    hi.x = pk_bf16_rn(t0, t1);
    hi.y = pk_bf16_rn(t2, t3);
    float f0 = __builtin_bit_cast(float, hi.x << 16);
    float f1 = __builtin_bit_cast(float, hi.x & 0xFFFF0000u);
    float f2 = __builtin_bit_cast(float, hi.y << 16);
    float f3 = __builtin_bit_cast(float, hi.y & 0xFFFF0000u);
    lo.x = pk_bf16_rn(t0 - f0, t1 - f1);
    lo.y = pk_bf16_rn(t2 - f2, t3 - f3);
}

__device__ __forceinline__ void vel_shock(float pC, float rho, float p, float v, float sign,
                                          float& rhoC, float& hC, float& vstar, float& Vs){
    float h  = fmaf(G_OVER_GM1_F, fdiv(p, rho), 1.0f);
    float W  = rsq_f(1.0f - v * v);
    float dp = p - pC;
    float t  = fdiv(GM1_F * dp, GAMMA_F * pC);
    float A  = 1.0f + t;
    float B  = -t;
    float C  = fdiv(h * dp, rho) - h * h;
    float disc = fmaxf(B * B - 4.0f * A * C, 0.0f);
    hC   = fdiv(-B + sqrtf(disc), 2.0f * A);
    rhoC = fdiv(GAMMA_F * pC, GM1_F * (hC - 1.0f));
    float j2 = fmaxf(fdiv(pC - p, fdiv(h, rho) - fdiv(hC, rhoC)), 1e-12f);
    float jabs = sqrtf(j2);
    float rw = rho * W;
    float a2 = rw * rw;
    Vs = fdiv(a2 * v + sign * jabs * sqrtf(j2 + a2 * (1.0f - v * v)), a2 + j2);
    float Ws = rsq_f(fmaxf(1.0f - Vs * Vs, 1e-12f));
    float js = sign * jabs;
    vstar = fdiv(h * W * v + fdiv(Ws * (pC - p), js),
                 h * W + (pC - p) * (fdiv(Ws * v, js) + rcp_f(rho * W)));
}

// ---------- prep: build per-lane split-bf16 MFMA A-fragments of W1, W2 ----------
__global__ __launch_bounds__(64) void prep_frags(
    const float* __restrict__ W1, const float* __restrict__ W2,
    unsigned short* __restrict__ ws)
{
    const int e = blockIdx.x;      // 0..7
    const int l = threadIdx.x;     // 0..63
    const int g = l >> 4, q = l & 15;

    // W1^T frag: A[row=16mt+q][k=8g+jj] = W1[e][k][16mt+q], zero-padded k>=6
    for (int mt = 0; mt < 4; ++mt){
        for (int jj = 0; jj < 8; ++jj){
            int k = 8 * g + jj;
            float w = (k < 6) ? W1[(e * 6 + k) * 64 + 16 * mt + q] : 0.0f;
            unsigned hb, lb; split2(w, hb, lb);
            ws[((((size_t)e * 4 + mt) * 2 + 0) * 64 + l) * 8 + jj] = (unsigned short)hb;
            ws[((((size_t)e * 4 + mt) * 2 + 1) * 64 + l) * 8 + jj] = (unsigned short)lb;
        }
    }
    // W2^T frag: A[row=16mt+q][k=32ks+8g+jj] = W2[e][k][16mt+q]
    for (int ks = 0; ks < 2; ++ks)
    for (int mt = 0; mt < 4; ++mt)
    for (int jj = 0; jj < 8; ++jj){
        int k = 32 * ks + 8 * g + jj;
        float w = W2[((size_t)e * 64 + k) * 64 + 16 * mt + q];
        unsigned hb, lb; split2(w, hb, lb);
        ws[WS1_SHORTS + ((((((size_t)e * 2 + ks) * 4 + mt) * 2 + 0) * 64 + l) * 8 + jj)] = (unsigned short)hb;
        ws[WS1_SHORTS + ((((((size_t)e * 2 + ks) * 4 + mt) * 2 + 1) * 64 + l) * 8 + jj)] = (unsigned short)lb;
    }
}

// ---------- main: one wave owns 64 cells ----------
__global__ __launch_bounds__(64, 4) void shock_mfma_kernel(
    const float* __restrict__ P, const float* __restrict__ F,
    const unsigned short* __restrict__ ws,
    const float* __restrict__ b1, const float* __restrict__ b2,
    const float* __restrict__ W3, const float* __restrict__ b3,
    float* __restrict__ out, int N)
{
    // half-cell h1 buffer: 32 cells x 64 k, hi+lo = 8KB total
    __shared__ unsigned short h1hi[32 * 64];
    __shared__ unsigned short h1lo[32 * 64];

    const int l = threadIdx.x;
    const int g = l >> 4;
    const int q = l & 15;
    const int n  = blockIdx.x * 64 + l;
    const int nc = (n < N) ? n : (N - 1);

    const float2* P2 = reinterpret_cast<const float2*>(P + (size_t)nc * 6);
    float2 c0 = P2[0], c1 = P2[1], c2 = P2[2];
    float rhoL = c0.x, rhoR = c0.y;
    float pL   = c1.x, pR   = c1.y;
    float vL   = c2.x, vR   = c2.y;

    float aP = fmaxf(pL, pR);

    // ---- build x B-frags (ensemble-invariant, once): lane supplies B[k=8g+jj][cell=16ct+q]
    v8s xbh[4], xbl[4];
    {
        float x0 = __logf(rhoL), x1 = __logf(rhoR);
        float x2 = __logf(pL),   x3 = __logf(pR);
        unsigned xh[4], xl[4];
        unsigned h0, l0, h1_, l1_;
        split2(x0, h0, l0); split2(x1, h1_, l1_); xh[0] = h0 | (h1_ << 16); xl[0] = l0 | (l1_ << 16);
        split2(x2, h0, l0); split2(x3, h1_, l1_); xh[1] = h0 | (h1_ << 16); xl[1] = l0 | (l1_ << 16);
        split2(vL, h0, l0); split2(vR, h1_, l1_); xh[2] = h0 | (h1_ << 16); xl[2] = l0 | (l1_ << 16);
        xh[3] = 0u; xl[3] = 0u;
        #pragma unroll
        for (int ct = 0; ct < 4; ++ct){
            int src = 16 * ct + q;
            #pragma unroll
            for (int w = 0; w < 4; ++w){
                unsigned vh = (unsigned)__shfl((int)xh[w], src, 64);
                unsigned vl = (unsigned)__shfl((int)xl[w], src, 64);
                if (g != 0){ vh = 0u; vl = 0u; }
                xbh[ct][2*w]   = (short)(vh & 0xFFFFu);
                xbh[ct][2*w+1] = (short)(vh >> 16);
                xbl[ct][2*w]   = (short)(vl & 0xFFFFu);
                xbl[ct][2*w+1] = (short)(vl >> 16);
            }
        }
    }

    const int swzW = (q & 7) << 3;   // cell-row swizzle for LDS (c' & 7 == q & 7 always)

    float bestGap = 0.0f;
    float s_pC = 0.0f, s_rhoCL = 0.0f, s_hCL = 0.0f, s_vstarL = 0.0f, s_VsL = 0.0f;
    float s_rhoCR = 0.0f, s_hCR = 0.0f, s_vstarR = 0.0f, s_VsR = 0.0f;

    #pragma unroll 1
    for (int e = 0; e < 8; ++e){
        const v8s* wsA1 = reinterpret_cast<const v8s*>(ws) + (size_t)e * 4 * 2 * 64;
        const v8s* wsA2 = reinterpret_cast<const v8s*>(ws + WS1_SHORTS) + (size_t)e * 2 * 4 * 2 * 64;
        float z[4];
        #pragma unroll
        for (int i = 0; i < 4; ++i) z[i] = 0.0f;

        #pragma unroll
        for (int half = 0; half < 2; ++half){
            // ---- phase 1: h1 rows for cells [32*half, 32*half+32) -> LDS
            #pragma unroll
            for (int mt = 0; mt < 4; ++mt){
                v8s a1h = wsA1[(mt * 2 + 0) * 64 + l];
                v8s a1l = wsA1[(mt * 2 + 1) * 64 + l];
                v4f bias = *reinterpret_cast<const v4f*>(b1 + e * 64 + 16 * mt + 4 * g);
                #pragma unroll
                for (int ct2 = 0; ct2 < 2; ++ct2){
                    int ct = 2 * half + ct2;
                    v4f d = bias;
                    d = __builtin_amdgcn_mfma_f32_16x16x32_bf16(a1h, xbh[ct], d, 0, 0, 0);
                    d = __builtin_amdgcn_mfma_f32_16x16x32_bf16(a1h, xbl[ct], d, 0, 0, 0);
                    d = __builtin_amdgcn_mfma_f32_16x16x32_bf16(a1l, xbh[ct], d, 0, 0, 0);
                    float t0 = fast_tanh(d[0]), t1 = fast_tanh(d[1]);
                    float t2 = fast_tanh(d[2]), t3 = fast_tanh(d[3]);
                    uint2 hp, lp;
                    split_pack4(t0, t1, t2, t3, hp, lp);
                    int cp  = q + 16 * ct2;                       // cell-row in half-buffer
                    int idx = cp * 64 + ((16 * mt + 4 * g) ^ swzW);
                    *reinterpret_cast<uint2*>(&h1hi[idx]) = hp;
                    *reinterpret_cast<uint2*>(&h1lo[idx]) = lp;
                }
            }
            // ---- phase 2: L2+L3 for these cells
            #pragma unroll
            for (int ct2 = 0; ct2 < 2; ++ct2){
                int ct = 2 * half + ct2;
                int cp = q + 16 * ct2;
                int r0 = cp * 64 + ((8 * g +  0) ^ swzW);
                int r1 = cp * 64 + ((8 * g + 32) ^ swzW);
                v8s bh0 = *reinterpret_cast<const v8s*>(&h1hi[r0]);
                v8s bl0 = *reinterpret_cast<const v8s*>(&h1lo[r0]);
                v8s bh1 = *reinterpret_cast<const v8s*>(&h1hi[r1]);
                v8s bl1 = *reinterpret_cast<const v8s*>(&h1lo[r1]);
                #pragma unroll
                for (int mt = 0; mt < 4; ++mt){
                    v8s a2h0 = wsA2[((0 * 4 + mt) * 2 + 0) * 64 + l];
                    v8s a2l0 = wsA2[((0 * 4 + mt) * 2 + 1) * 64 + l];
                    v8s a2h1 = wsA2[((1 * 4 + mt) * 2 + 0) * 64 + l];
                    v8s a2l1 = wsA2[((1 * 4 + mt) * 2 + 1) * 64 + l];
                    v4f d = *reinterpret_cast<const v4f*>(b2 + e * 64 + 16 * mt + 4 * g);
                    d = __builtin_amdgcn_mfma_f32_16x16x32_bf16(a2h0, bh0, d, 0, 0, 0);
                    d = __builtin_amdgcn_mfma_f32_16x16x32_bf16(a2h0, bl0, d, 0, 0, 0);
                    d = __builtin_amdgcn_mfma_f32_16x16x32_bf16(a2l0, bh0, d, 0, 0, 0);
                    d = __builtin_amdgcn_mfma_f32_16x16x32_bf16(a2h1, bh1, d, 0, 0, 0);
                    d = __builtin_amdgcn_mfma_f32_16x16x32_bf16(a2h1, bl1, d, 0, 0, 0);
                    d = __builtin_amdgcn_mfma_f32_16x16x32_bf16(a2l1, bh1, d, 0, 0, 0);
                    v4f w3v = *reinterpret_cast<const v4f*>(W3 + e * 64 + 16 * mt + 4 * g);
                    z[ct] = fmaf(fast_tanh(d[0]), w3v[0], z[ct]);
                    z[ct] = fmaf(fast_tanh(d[1]), w3v[1], z[ct]);
                    z[ct] = fmaf(fast_tanh(d[2]), w3v[2], z[ct]);
                    z[ct] = fmaf(fast_tanh(d[3]), w3v[3], z[ct]);
                }
            }
        }

        // ---- reduce partial z over the 4 lane-groups; lane's own cell is ct=g
        #pragma unroll
        for (int ct = 0; ct < 4; ++ct){
            z[ct] += __shfl_xor(z[ct], 16, 64);
            z[ct] += __shfl_xor(z[ct], 32, 64);
        }
        float zown = (g == 0) ? z[0] : (g == 1) ? z[1] : (g == 2) ? z[2] : z[3];
        float z3 = zown + b3[e];
        // (1+sigmoid(z))/(1-sigmoid(z)) == 1 + 2*e^z
        float pC = aP * fmaf(2.0f, __expf(z3), 1.0f);

        float rhoCL, hCL, vstarL, VsL, rhoCR, hCR, vstarR, VsR;
        vel_shock(pC, rhoL, pL, vL, -1.0f, rhoCL, hCL, vstarL, VsL);
        vel_shock(pC, rhoR, pR, vR, +1.0f, rhoCR, hCR, vstarR, VsR);

        float gap = fabsf(vstarL - vstarR);
        bool take = (e == 0) || (gap < bestGap);
        if (take){
            bestGap = gap; s_pC = pC;
            s_rhoCL = rhoCL; s_hCL = hCL; s_vstarL = vstarL; s_VsL = VsL;
            s_rhoCR = rhoCR; s_hCR = hCR; s_vstarR = vstarR; s_VsR = VsR;
        }
    }

    if (n < N){
        float lambdaC = 0.5f * (s_vstarR + s_vstarL);
        float WC = rsq_f(1.0f - lambdaC * lambdaC);
        float densCL = WC * s_rhoCL;
        float densCR = WC * s_rhoCR;
        float momCL = WC * WC * s_rhoCL * s_hCL * lambdaC;
        float momCR = WC * WC * s_rhoCR * s_hCR * lambdaC;

        float FCL0 = densCL * lambdaC;
        float FCL1 = densCL * (WC * s_hCL - 1.0f) * lambdaC;
        float FCL2 = momCL * lambdaC + s_pC;
        float FCR0 = densCR * lambdaC;
        float FCR1 = densCR * (WC * s_hCR - 1.0f) * lambdaC;
        float FCR2 = momCR * lambdaC + s_pC;

        const float2* F2 = reinterpret_cast<const float2*>(F + (size_t)n * 6);
        float2 f0p = F2[0], f1p = F2[1], f2p = F2[2];

        float f0 = 0.0f, f1 = 0.0f, f2 = 0.0f;
        if (s_VsL >= 0.0f)                    { f0 = f0p.x; f1 = f1p.x; f2 = f2p.x; }
        if (s_VsL < 0.0f && lambdaC > 0.0f)   { f0 = FCL0;  f1 = FCL1;  f2 = FCL2; }
        if (lambdaC <= 0.0f && s_VsR > 0.0f)  { f0 = FCR0;  f1 = FCR1;  f2 = FCR2; }
        if (s_VsR <= 0.0f)                    { f0 = f0p.y; f1 = f1p.y; f2 = f2p.y; }

        out[(size_t)n * 3 + 0] = f0;
        out[(size_t)n * 3 + 1] = f1;
        out[(size_t)n * 3 + 2] = f2;
    }
}

extern "C" void kernel_launch(void* const* d_in, const int* in_sizes, int n_in,
                              void* d_out, int out_size, void* d_ws, size_t ws_size,
                              hipStream_t stream) {
    const float* P  = (const float*)d_in[0];
    const float* F  = (const float*)d_in[2];
    const float* W1 = (const float*)d_in[5];
    const float* b1 = (const float*)d_in[6];
    const float* W2 = (const float*)d_in[7];
    const float* b2 = (const float*)d_in[8];
    const float* W3 = (const float*)d_in[9];
    const float* b3 = (const float*)d_in[10];
    float* out = (float*)d_out;
    unsigned short* ws = (unsigned short*)d_ws;

    int N = in_sizes[0] / 6;

    prep_frags<<<8, 64, 0, stream>>>(W1, W2, ws);

    int grid = (N + 63) / 64;
    shock_mfma_kernel<<<grid, 64, 0, stream>>>(P, F, ws, b1, b2, W3, b3, out, N);
}

// Round 5
// 553.284 us; speedup vs baseline: 1.4594x; 1.4594x over previous
//
#include <hip/hip_runtime.h>

typedef short v8s __attribute__((ext_vector_type(8)));   // 8 bf16 (4 VGPRs) MFMA frag
typedef float v4f __attribute__((ext_vector_type(4)));   // 4 f32 MFMA acc

#define GAMMA_F       ((float)(5.0/3.0))
#define GM1_F         ((float)(5.0/3.0 - 1.0))
#define G_OVER_GM1_F  2.5f

// ws layout (shorts): ws1 = W1 frags [e][mt][hl][lane][8]  = 8*4*2*64*8  shorts (64KB)
//                     ws2 = W2 frags [e][ks][mt][hl][lane][8] = 8*2*4*2*64*8 shorts (128KB)
#define WS1_SHORTS (8 * 4 * 2 * 64 * 8)

__device__ __forceinline__ float rcp_f(float x){ return __builtin_amdgcn_rcpf(x); }
__device__ __forceinline__ float rsq_f(float x){ return __builtin_amdgcn_rsqf(x); }
__device__ __forceinline__ float fdiv(float a, float b){ return a * __builtin_amdgcn_rcpf(b); }

__device__ __forceinline__ float fast_tanh(float x){
    float e = __expf(2.0f * x);
    return fmaf(-2.0f, rcp_f(e + 1.0f), 1.0f);
}

// exact RTNE float->bf16 bit math
__device__ __forceinline__ unsigned bfbits(float f){
    unsigned u = __builtin_bit_cast(unsigned, f);
    return (u + 0x7FFFu + ((u >> 16) & 1u)) >> 16;
}
__device__ __forceinline__ void split2(float f, unsigned& hi, unsigned& lo){
    hi = bfbits(f);
    float fh = __builtin_bit_cast(float, hi << 16);
    lo = bfbits(f - fh);
}

// RTNE packed pair via v_cvt_pk_bf16_f32 (no builtin on gfx950 -> inline asm).
// Result: lo16 = bf16(a), hi16 = bf16(b).
__device__ __forceinline__ unsigned pk_bf16_rn(float a, float b){
    unsigned r;
    asm("v_cvt_pk_bf16_f32 %0, %1, %2" : "=v"(r) : "v"(a), "v"(b));
    return r;
}
// 4 floats -> hi-pack uint2 + lo-pack uint2 (hi + lo == split-bf16, RTNE both)
__device__ __forceinline__ void split_pack4(const float t0, const float t1, const float t2, const float t3,
                                            uint2& hi, uint2& lo){
    hi.x = pk_bf16_rn(t0, t1);
    hi.y = pk_bf16_rn(t2, t3);
    float f0 = __builtin_bit_cast(float, hi.x << 16);
    float f1 = __builtin_bit_cast(float, hi.x & 0xFFFF0000u);
    float f2 = __builtin_bit_cast(float, hi.y << 16);
    float f3 = __builtin_bit_cast(float, hi.y & 0xFFFF0000u);
    lo.x = pk_bf16_rn(t0 - f0, t1 - f1);
    lo.y = pk_bf16_rn(t2 - f2, t3 - f3);
}

__device__ __forceinline__ void vel_shock(float pC, float rho, float p, float v, float sign,
                                          float& rhoC, float& hC, float& vstar, float& Vs){
    float h  = fmaf(G_OVER_GM1_F, fdiv(p, rho), 1.0f);
    float W  = rsq_f(1.0f - v * v);
    float dp = p - pC;
    float t  = fdiv(GM1_F * dp, GAMMA_F * pC);
    float A  = 1.0f + t;
    float B  = -t;
    float C  = fdiv(h * dp, rho) - h * h;
    float disc = fmaxf(B * B - 4.0f * A * C, 0.0f);
    hC   = fdiv(-B + sqrtf(disc), 2.0f * A);
    rhoC = fdiv(GAMMA_F * pC, GM1_F * (hC - 1.0f));
    float j2 = fmaxf(fdiv(pC - p, fdiv(h, rho) - fdiv(hC, rhoC)), 1e-12f);
    float jabs = sqrtf(j2);
    float rw = rho * W;
    float a2 = rw * rw;
    Vs = fdiv(a2 * v + sign * jabs * sqrtf(j2 + a2 * (1.0f - v * v)), a2 + j2);
    float Ws = rsq_f(fmaxf(1.0f - Vs * Vs, 1e-12f));
    float js = sign * jabs;
    vstar = fdiv(h * W * v + fdiv(Ws * (pC - p), js),
                 h * W + (pC - p) * (fdiv(Ws * v, js) + rcp_f(rho * W)));
}

// ---------- prep: build per-lane split-bf16 MFMA A-fragments of W1, W2 ----------
__global__ __launch_bounds__(64) void prep_frags(
    const float* __restrict__ W1, const float* __restrict__ W2,
    unsigned short* __restrict__ ws)
{
    const int e = blockIdx.x;      // 0..7
    const int l = threadIdx.x;     // 0..63
    const int g = l >> 4, q = l & 15;

    // W1^T frag: A[row=16mt+q][k=8g+jj] = W1[e][k][16mt+q], zero-padded k>=6
    for (int mt = 0; mt < 4; ++mt){
        for (int jj = 0; jj < 8; ++jj){
            int k = 8 * g + jj;
            float w = (k < 6) ? W1[(e * 6 + k) * 64 + 16 * mt + q] : 0.0f;
            unsigned hb, lb; split2(w, hb, lb);
            ws[((((size_t)e * 4 + mt) * 2 + 0) * 64 + l) * 8 + jj] = (unsigned short)hb;
            ws[((((size_t)e * 4 + mt) * 2 + 1) * 64 + l) * 8 + jj] = (unsigned short)lb;
        }
    }
    // W2^T frag: A[row=16mt+q][k=32ks+8g+jj] = W2[e][k][16mt+q]
    for (int ks = 0; ks < 2; ++ks)
    for (int mt = 0; mt < 4; ++mt)
    for (int jj = 0; jj < 8; ++jj){
        int k = 32 * ks + 8 * g + jj;
        float w = W2[((size_t)e * 64 + k) * 64 + 16 * mt + q];
        unsigned hb, lb; split2(w, hb, lb);
        ws[WS1_SHORTS + ((((((size_t)e * 2 + ks) * 4 + mt) * 2 + 0) * 64 + l) * 8 + jj)] = (unsigned short)hb;
        ws[WS1_SHORTS + ((((((size_t)e * 2 + ks) * 4 + mt) * 2 + 1) * 64 + l) * 8 + jj)] = (unsigned short)lb;
    }
}

// ---------- main: one wave owns 64 cells ----------
__global__ __launch_bounds__(64, 2) void shock_mfma_kernel(
    const float* __restrict__ P, const float* __restrict__ F,
    const unsigned short* __restrict__ ws,
    const float* __restrict__ b1, const float* __restrict__ b2,
    const float* __restrict__ W3, const float* __restrict__ b3,
    float* __restrict__ out, int N)
{
    // full 64-cell h1 buffer: 64 cells x 64 k, hi+lo = 16KB
    __shared__ unsigned short h1hi[64 * 64];
    __shared__ unsigned short h1lo[64 * 64];

    const int l = threadIdx.x;
    const int g = l >> 4;
    const int q = l & 15;
    const int n  = blockIdx.x * 64 + l;
    const int nc = (n < N) ? n : (N - 1);

    const float2* P2 = reinterpret_cast<const float2*>(P + (size_t)nc * 6);
    float2 c0 = P2[0], c1 = P2[1], c2 = P2[2];
    float rhoL = c0.x, rhoR = c0.y;
    float pL   = c1.x, pR   = c1.y;
    float vL   = c2.x, vR   = c2.y;

    float aP = fmaxf(pL, pR);

    // ---- build x B-frags (ensemble-invariant, once): lane supplies B[k=8g+jj][cell=16ct+q]
    v8s xbh[4], xbl[4];
    {
        float x0 = __logf(rhoL), x1 = __logf(rhoR);
        float x2 = __logf(pL),   x3 = __logf(pR);
        unsigned xh[4], xl[4];
        unsigned h0, l0, h1_, l1_;
        split2(x0, h0, l0); split2(x1, h1_, l1_); xh[0] = h0 | (h1_ << 16); xl[0] = l0 | (l1_ << 16);
        split2(x2, h0, l0); split2(x3, h1_, l1_); xh[1] = h0 | (h1_ << 16); xl[1] = l0 | (l1_ << 16);
        split2(vL, h0, l0); split2(vR, h1_, l1_); xh[2] = h0 | (h1_ << 16); xl[2] = l0 | (l1_ << 16);
        xh[3] = 0u; xl[3] = 0u;
        #pragma unroll
        for (int ct = 0; ct < 4; ++ct){
            int src = 16 * ct + q;
            #pragma unroll
            for (int w = 0; w < 4; ++w){
                unsigned vh = (unsigned)__shfl((int)xh[w], src, 64);
                unsigned vl = (unsigned)__shfl((int)xl[w], src, 64);
                if (g != 0){ vh = 0u; vl = 0u; }
                xbh[ct][2*w]   = (short)(vh & 0xFFFFu);
                xbh[ct][2*w+1] = (short)(vh >> 16);
                xbl[ct][2*w]   = (short)(vl & 0xFFFFu);
                xbl[ct][2*w+1] = (short)(vl >> 16);
            }
        }
    }

    const int swzW = (q & 7) << 3;   // cell-row swizzle for LDS (c & 7 == q & 7 always)

    float bestGap = 0.0f;
    float s_pC = 0.0f, s_rhoCL = 0.0f, s_hCL = 0.0f, s_vstarL = 0.0f, s_VsL = 0.0f;
    float s_rhoCR = 0.0f, s_hCR = 0.0f, s_vstarR = 0.0f, s_VsR = 0.0f;

    #pragma unroll 1
    for (int e = 0; e < 8; ++e){
        const v8s* wsA1 = reinterpret_cast<const v8s*>(ws) + (size_t)e * 4 * 2 * 64;
        const v8s* wsA2 = reinterpret_cast<const v8s*>(ws + WS1_SHORTS) + (size_t)e * 2 * 4 * 2 * 64;

        // ---- hoisted fragment loads: 24 independent dwordx4, consumed a phase later
        v8s a1h[4], a1l[4];
        #pragma unroll
        for (int mt = 0; mt < 4; ++mt){
            a1h[mt] = wsA1[(mt * 2 + 0) * 64 + l];
            a1l[mt] = wsA1[(mt * 2 + 1) * 64 + l];
        }
        v8s a2h[2][4], a2l[2][4];
        #pragma unroll
        for (int ks = 0; ks < 2; ++ks)
        #pragma unroll
        for (int mt = 0; mt < 4; ++mt){
            a2h[ks][mt] = wsA2[((ks * 4 + mt) * 2 + 0) * 64 + l];
            a2l[ks][mt] = wsA2[((ks * 4 + mt) * 2 + 1) * 64 + l];
        }

        float z[4];
        #pragma unroll
        for (int i = 0; i < 4; ++i) z[i] = 0.0f;

        // ---- phase 1: all 64 cells' h1 -> LDS
        #pragma unroll
        for (int mt = 0; mt < 4; ++mt){
            v4f bias = *reinterpret_cast<const v4f*>(b1 + e * 64 + 16 * mt + 4 * g);
            #pragma unroll
            for (int ct = 0; ct < 4; ++ct){
                v4f d = bias;
                d = __builtin_amdgcn_mfma_f32_16x16x32_bf16(a1h[mt], xbh[ct], d, 0, 0, 0);
                d = __builtin_amdgcn_mfma_f32_16x16x32_bf16(a1h[mt], xbl[ct], d, 0, 0, 0);
                d = __builtin_amdgcn_mfma_f32_16x16x32_bf16(a1l[mt], xbh[ct], d, 0, 0, 0);
                float t0 = fast_tanh(d[0]), t1 = fast_tanh(d[1]);
                float t2 = fast_tanh(d[2]), t3 = fast_tanh(d[3]);
                uint2 hp, lp;
                split_pack4(t0, t1, t2, t3, hp, lp);
                int idx = (16 * ct + q) * 64 + ((16 * mt + 4 * g) ^ swzW);
                *reinterpret_cast<uint2*>(&h1hi[idx]) = hp;
                *reinterpret_cast<uint2*>(&h1lo[idx]) = lp;
            }
        }

        // ---- phase 2: L2+L3 for all cells
        #pragma unroll
        for (int ct = 0; ct < 4; ++ct){
            int c  = 16 * ct + q;
            int r0 = c * 64 + ((8 * g +  0) ^ swzW);
            int r1 = c * 64 + ((8 * g + 32) ^ swzW);
            v8s bh0 = *reinterpret_cast<const v8s*>(&h1hi[r0]);
            v8s bl0 = *reinterpret_cast<const v8s*>(&h1lo[r0]);
            v8s bh1 = *reinterpret_cast<const v8s*>(&h1hi[r1]);
            v8s bl1 = *reinterpret_cast<const v8s*>(&h1lo[r1]);
            #pragma unroll
            for (int mt = 0; mt < 4; ++mt){
                v4f d = *reinterpret_cast<const v4f*>(b2 + e * 64 + 16 * mt + 4 * g);
                d = __builtin_amdgcn_mfma_f32_16x16x32_bf16(a2h[0][mt], bh0, d, 0, 0, 0);
                d = __builtin_amdgcn_mfma_f32_16x16x32_bf16(a2h[0][mt], bl0, d, 0, 0, 0);
                d = __builtin_amdgcn_mfma_f32_16x16x32_bf16(a2l[0][mt], bh0, d, 0, 0, 0);
                d = __builtin_amdgcn_mfma_f32_16x16x32_bf16(a2h[1][mt], bh1, d, 0, 0, 0);
                d = __builtin_amdgcn_mfma_f32_16x16x32_bf16(a2h[1][mt], bl1, d, 0, 0, 0);
                d = __builtin_amdgcn_mfma_f32_16x16x32_bf16(a2l[1][mt], bh1, d, 0, 0, 0);
                v4f w3v = *reinterpret_cast<const v4f*>(W3 + e * 64 + 16 * mt + 4 * g);
                z[ct] = fmaf(fast_tanh(d[0]), w3v[0], z[ct]);
                z[ct] = fmaf(fast_tanh(d[1]), w3v[1], z[ct]);
                z[ct] = fmaf(fast_tanh(d[2]), w3v[2], z[ct]);
                z[ct] = fmaf(fast_tanh(d[3]), w3v[3], z[ct]);
            }
        }

        // ---- reduce partial z over the 4 lane-groups; lane's own cell is ct=g
        #pragma unroll
        for (int ct = 0; ct < 4; ++ct){
            z[ct] += __shfl_xor(z[ct], 16, 64);
            z[ct] += __shfl_xor(z[ct], 32, 64);
        }
        float zown = (g == 0) ? z[0] : (g == 1) ? z[1] : (g == 2) ? z[2] : z[3];
        float z3 = zown + b3[e];
        // (1+sigmoid(z))/(1-sigmoid(z)) == 1 + 2*e^z
        float pC = aP * fmaf(2.0f, __expf(z3), 1.0f);

        float rhoCL, hCL, vstarL, VsL, rhoCR, hCR, vstarR, VsR;
        vel_shock(pC, rhoL, pL, vL, -1.0f, rhoCL, hCL, vstarL, VsL);
        vel_shock(pC, rhoR, pR, vR, +1.0f, rhoCR, hCR, vstarR, VsR);

        float gap = fabsf(vstarL - vstarR);
        bool take = (e == 0) || (gap < bestGap);
        if (take){
            bestGap = gap; s_pC = pC;
            s_rhoCL = rhoCL; s_hCL = hCL; s_vstarL = vstarL; s_VsL = VsL;
            s_rhoCR = rhoCR; s_hCR = hCR; s_vstarR = vstarR; s_VsR = VsR;
        }
    }

    if (n < N){
        float lambdaC = 0.5f * (s_vstarR + s_vstarL);
        float WC = rsq_f(1.0f - lambdaC * lambdaC);
        float densCL = WC * s_rhoCL;
        float densCR = WC * s_rhoCR;
        float momCL = WC * WC * s_rhoCL * s_hCL * lambdaC;
        float momCR = WC * WC * s_rhoCR * s_hCR * lambdaC;

        float FCL0 = densCL * lambdaC;
        float FCL1 = densCL * (WC * s_hCL - 1.0f) * lambdaC;
        float FCL2 = momCL * lambdaC + s_pC;
        float FCR0 = densCR * lambdaC;
        float FCR1 = densCR * (WC * s_hCR - 1.0f) * lambdaC;
        float FCR2 = momCR * lambdaC + s_pC;

        const float2* F2 = reinterpret_cast<const float2*>(F + (size_t)n * 6);
        float2 f0p = F2[0], f1p = F2[1], f2p = F2[2];

        float f0 = 0.0f, f1 = 0.0f, f2 = 0.0f;
        if (s_VsL >= 0.0f)                    { f0 = f0p.x; f1 = f1p.x; f2 = f2p.x; }
        if (s_VsL < 0.0f && lambdaC > 0.0f)   { f0 = FCL0;  f1 = FCL1;  f2 = FCL2; }
        if (lambdaC <= 0.0f && s_VsR > 0.0f)  { f0 = FCR0;  f1 = FCR1;  f2 = FCR2; }
        if (s_VsR <= 0.0f)                    { f0 = f0p.y; f1 = f1p.y; f2 = f2p.y; }

        out[(size_t)n * 3 + 0] = f0;
        out[(size_t)n * 3 + 1] = f1;
        out[(size_t)n * 3 + 2] = f2;
    }
}

extern "C" void kernel_launch(void* const* d_in, const int* in_sizes, int n_in,
                              void* d_out, int out_size, void* d_ws, size_t ws_size,
                              hipStream_t stream) {
    const float* P  = (const float*)d_in[0];
    const float* F  = (const float*)d_in[2];
    const float* W1 = (const float*)d_in[5];
    const float* b1 = (const float*)d_in[6];
    const float* W2 = (const float*)d_in[7];
    const float* b2 = (const float*)d_in[8];
    const float* W3 = (const float*)d_in[9];
    const float* b3 = (const float*)d_in[10];
    float* out = (float*)d_out;
    unsigned short* ws = (unsigned short*)d_ws;

    int N = in_sizes[0] / 6;

    prep_frags<<<8, 64, 0, stream>>>(W1, W2, ws);

    int grid = (N + 63) / 64;
    shock_mfma_kernel<<<grid, 64, 0, stream>>>(P, F, ws, b1, b2, W3, b3, out, N);
}